// Round 9
// baseline (431.699 us; speedup 1.0000x reference)
//
#include <hip/hip_runtime.h>
#include <stdint.h>

#define SEQ 8192
#define NCH 64                      // chunks per sequence (chunk = 128 steps)
#define NBLK 2048                   // 32 batches * 64 chunks

typedef float f32x4 __attribute__((ext_vector_type(4)));
typedef short short8 __attribute__((ext_vector_type(8)));
typedef unsigned short u16;
typedef u16 ushort8 __attribute__((ext_vector_type(8)));
typedef u16 ushort4v __attribute__((ext_vector_type(4)));
typedef unsigned long long u64;

__device__ __forceinline__ u16 f2bf(float f) {
  uint32_t u = __float_as_uint(f);
  u += 0x7fffu + ((u >> 16) & 1u);   // round-to-nearest-even
  return (u16)(u >> 16);
}

// async 16B global->LDS (lds dest wave-uniform base; HW adds lane*16)
__device__ __forceinline__ void gld16(void* lds, const void* g) {
  __builtin_amdgcn_global_load_lds(
      (const __attribute__((address_space(1))) uint32_t*)g,
      (__attribute__((address_space(3))) uint32_t*)lds, 16, 0, 0);
}

// ---------- emb f32 -> bf16 table + zero sync area (one-time per launch) ----------
__global__ void embq_kernel(const float* __restrict__ emb, u16* __restrict__ embq,
                            int* __restrict__ syncA) {
  int g = blockIdx.x * 256 + threadIdx.x;
  if (g < 1 + NBLK) syncA[g] = 0;          // ticket + flags
  int i = g * 4;                            // 8,192,000 elements exactly
  float4 v = *(const float4*)(emb + i);
  ushort4v p;
  p[0] = f2bf(v.x); p[1] = f2bf(v.y); p[2] = f2bf(v.z); p[3] = f2bf(v.w);
  *(ushort4v*)(embq + i) = p;
}

// ---------- weight preprocess: f32 [l][k][d] -> bf16 swizzled 8KB tiles ----------
// WtS: 64 tiles of 8192 BYTES, tile index (mat*4 + dh)*4 + kt, in-tile [64 dloc][64 kl],
// byte = (dloc*128 + kl*2) ^ ((dloc&7)<<4).  mat: 0=Wz l0,1=Wz l1,2=Wh l0,3=Wh l1
__global__ void wt_kernel(const float* __restrict__ Wz, const float* __restrict__ Wh,
                          u16* __restrict__ WtS) {
  int idx = blockIdx.x * 256 + threadIdx.x;   // 4*65536
  int d = idx & 255;
  int k = (idx >> 8) & 255;
  int m = idx >> 16;
  const float* src = (m < 2 ? Wz : Wh) + (size_t)(m & 1) * 65536;
  float v = src[k * 256 + d];
  int dh = d >> 6, dloc = d & 63, kt = k >> 6, kl = k & 63;
  size_t tile = ((size_t)(m * 4 + dh) * 4 + kt) * 8192;   // BYTES
  size_t byte = (size_t)((dloc * 128 + kl * 2) ^ ((dloc & 7) << 4));
  *(u16*)((char*)WtS + tile + byte) = f2bf(v);
}

// ---- stage one layer's kt B-tiles (w<4: Wz, w>=4: Wh), async ----
__device__ __forceinline__ void stageB(int lsel, int kt, const u16* WtS,
                                       u16* Bzs, u16* Bhs, int w, int lane) {
  const int dh = w & 3;
  const int mat = (w < 4) ? lsel : (2 + lsel);
  const char* g = (const char*)WtS + (size_t)((mat * 4 + dh) * 4 + kt) * 8192;
  char* dst = (w < 4) ? (char*)Bzs + dh * 8192 : (char*)Bhs + dh * 8192;
  #pragma unroll
  for (int i = 0; i < 8; i++)
    gld16(dst + i * 1024, g + i * 1024 + lane * 16);
}

// ---- 4-kt MFMA core (As holds full K=256 A-tile; B double-staged per kt) ----
__device__ __forceinline__ void gemm_core(int lsel, const u16* WtS,
    u16* As, u16* Bzs, u16* Bhs, int w, int wr, int wc, int l15, int lg, int lane,
    f32x4 (&accz)[2][8], f32x4 (&acch)[2][8])
{
  for (int kt = 0; kt < 4; kt++) {
    __syncthreads();                       // staging (and A writes) complete
    #pragma unroll
    for (int ks = 0; ks < 2; ks++) {
      const int xm = (l15 & 7) << 4;
      short8 fa[2];
      #pragma unroll
      for (int mi = 0; mi < 2; mi++)
        fa[mi] = *(const short8*)((const char*)As + kt * 16384 +
                   (((wr * 32 + mi * 16 + l15) * 128 + ks * 64 + lg * 16) ^ xm));
      #pragma unroll
      for (int ni = 0; ni < 8; ni++) {
        const int dh = wc * 2 + (ni >> 2);
        const int off = (((ni & 3) * 16 + l15) * 128 + ks * 64 + lg * 16) ^ xm;
        short8 fbz = *(const short8*)((const char*)Bzs + dh * 8192 + off);
        short8 fbh = *(const short8*)((const char*)Bhs + dh * 8192 + off);
        #pragma unroll
        for (int mi = 0; mi < 2; mi++) {
          accz[mi][ni] = __builtin_amdgcn_mfma_f32_16x16x32_bf16(fa[mi], fbz, accz[mi][ni], 0, 0, 0);
          acch[mi][ni] = __builtin_amdgcn_mfma_f32_16x16x32_bf16(fa[mi], fbh, acch[mi][ni], 0, 0, 0);
        }
      }
    }
    if (kt < 3) {
      __syncthreads();                     // B reads done before overwrite
      stageB(lsel, kt + 1, WtS, Bzs, Bhs, w, lane);
    }
  }
}

// ---------- the fused kernel: both layers + scan via decoupled lookback ----------
__global__ __launch_bounds__(512, 1)
void fused_kernel(const int* __restrict__ x, const u16* __restrict__ embq,
                  const u16* __restrict__ WtS,
                  const float* __restrict__ bz0, const float* __restrict__ bh0,
                  const float* __restrict__ bz1, const float* __restrict__ bh1,
                  u64* __restrict__ Loc0, float2* __restrict__ Loc1,
                  int* __restrict__ flag0, int* __restrict__ ticket)
{
  __shared__ __align__(16) u16 As[32768];    // 64KB union: A-tile / SegT / h1-tile
  __shared__ __align__(16) u16 Bzs[16384];   // 32KB: 4 dh-subtiles of 8KB
  __shared__ __align__(16) u16 Bhs[16384];   // 32KB
  __shared__ float hin[256];
  __shared__ int vb_sh;

  const int tid = threadIdx.x;
  const int lane = tid & 63;
  const int w = tid >> 6;
  const int wr = w >> 1, wc = w & 1;
  const int l15 = lane & 15, lg = lane >> 4;

  if (tid == 0) vb_sh = atomicAdd(ticket, 1);
  __syncthreads();
  const int vb = vb_sh;
  const int b = vb & 31;
  const int c = vb >> 5;                     // ticket order => c ascending => no deadlock
  const int cb = b * NCH + c;

  // ---- prologue: waves 4-7 stage layer-0 B(kt=0); waves 0-3 gather A ----
  if (w >= 4) {
    const int dh = w - 4;
    const char* gz = (const char*)WtS + (size_t)((0 * 4 + dh) * 4 + 0) * 8192;
    const char* gh = (const char*)WtS + (size_t)((2 * 4 + dh) * 4 + 0) * 8192;
    #pragma unroll
    for (int i = 0; i < 8; i++) {
      gld16((char*)Bzs + dh * 8192 + i * 1024, gz + i * 1024 + lane * 16);
      gld16((char*)Bhs + dh * 8192 + i * 1024, gh + i * 1024 + lane * 16);
    }
  } else {
    const int sm = tid >> 1, hb = tid & 1;
    const int tok = x[b * SEQ + c * 128 + sm];
    const u16* src = embq + (size_t)tok * 256 + hb * 128;
    char* sub = (char*)As + (hb * 2) * 16384;
    const int swz = (sm & 7) << 4;
    #pragma unroll
    for (int j = 0; j < 16; j++) {
      ushort8 p = *(const ushort8*)(src + j * 8);
      *(ushort8*)(sub + (j >> 3) * 16384 + ((sm * 128 + (j & 7) * 16) ^ swz)) = p;
    }
  }

  f32x4 accz[2][8], acch[2][8];
  #pragma unroll
  for (int i = 0; i < 2; i++)
    #pragma unroll
    for (int j = 0; j < 8; j++) {
      f32x4 zz = {0.f, 0.f, 0.f, 0.f};
      accz[i][j] = zz; acch[i][j] = zz;
    }

  gemm_core(0, WtS, As, Bzs, Bhs, w, wr, wc, l15, lg, lane, accz, acch);

  // ======== layer-0 epilogue ========
  __syncthreads();                           // E1: all MFMA done; As/B free
  stageB(1, 0, WtS, Bzs, Bhs, w, lane);      // async prefetch layer-1 kt0

  float2* SegT = (float2*)As;                // [32 seg][256 d]
  #pragma unroll
  for (int ni = 0; ni < 8; ni++) {
    const int d = wc * 128 + ni * 16 + l15;
    const float bzv = bz0[d];
    const float bhv = bh0[d];
    #pragma unroll
    for (int mi = 0; mi < 2; mi++) {
      float A = 1.f, B = 0.f;
      #pragma unroll
      for (int r = 0; r < 4; r++) {
        float zl = accz[mi][ni][r] + bzv;
        float zg = 1.f / (1.f + __expf(-zl));
        float ht = acch[mi][ni][r] + bhv;
        float a = 1.f - zg, bb = zg * ht;
        accz[mi][ni][r] = a;                 // keep a,b for h-rebuild
        acch[mi][ni][r] = bb;
        B = B * a + bb;
        A *= a;
      }
      SegT[(wr * 8 + mi * 4 + lg) * 256 + d] = make_float2(A, B);
    }
  }
  __syncthreads();                           // E2: SegT complete
  if (tid < 256) {
    float PA = 1.f, PB = 0.f;                // exclusive prefix over 32 segments
    #pragma unroll 8
    for (int s = 0; s < 32; s++) {
      float2 v = SegT[s * 256 + tid];
      SegT[s * 256 + tid] = make_float2(PA, PB);
      PB = v.x * PB + v.y;
      PA = v.x * PA;
    }
    u64 pv = (u64)__float_as_uint(PA) | ((u64)__float_as_uint(PB) << 32);
    __hip_atomic_store(&Loc0[cb * 256 + tid], pv, __ATOMIC_RELAXED, __HIP_MEMORY_SCOPE_AGENT);
    __threadfence();
  }
  __syncthreads();                           // E3: publishes done
  if (tid == 0)
    __hip_atomic_store(&flag0[cb], 1, __ATOMIC_RELEASE, __HIP_MEMORY_SCOPE_AGENT);
  if (w == 0 && c > 0) {
    while (true) {
      int ok = (lane < c) ? __hip_atomic_load(&flag0[b * NCH + lane],
                 __ATOMIC_RELAXED, __HIP_MEMORY_SCOPE_AGENT) : 1;
      if (__all(ok != 0)) break;
      __builtin_amdgcn_s_sleep(8);
    }
  }
  __syncthreads();                           // E4: all predecessor locals visible
  if (tid < 256) {                           // lookback compose (order j ascending)
    float H = 0.f;
    for (int j0 = 0; j0 < c; j0 += 8) {
      u64 v[8];
      #pragma unroll
      for (int k = 0; k < 8; k++)
        if (j0 + k < c)
          v[k] = __hip_atomic_load(&Loc0[(b * NCH + j0 + k) * 256 + tid],
                   __ATOMIC_RELAXED, __HIP_MEMORY_SCOPE_AGENT);
      #pragma unroll
      for (int k = 0; k < 8; k++)
        if (j0 + k < c) {
          float A = __uint_as_float((uint32_t)v[k]);
          float B = __uint_as_float((uint32_t)(v[k] >> 32));
          H = A * H + B;
        }
    }
    hin[tid] = H;
  }
  float ea[2][8], eb[2][8];                  // own exclusive prefixes
  #pragma unroll
  for (int mi = 0; mi < 2; mi++)
    #pragma unroll
    for (int ni = 0; ni < 8; ni++) {
      float2 e = SegT[(wr * 8 + mi * 4 + lg) * 256 + (wc * 128 + ni * 16 + l15)];
      ea[mi][ni] = e.x; eb[mi][ni] = e.y;
    }
  __syncthreads();                           // E5: SegT reads + hin done
  // ---- rebuild h1 tile (t-parallel) into As, bf16 swizzled ----
  #pragma unroll
  for (int ni = 0; ni < 8; ni++) {
    const int d = wc * 128 + ni * 16 + l15;
    char* sub = (char*)As + (d >> 6) * 16384;
    const int kl2 = (d & 63) * 2;
    const float h0 = hin[d];
    #pragma unroll
    for (int mi = 0; mi < 2; mi++) {
      float h = ea[mi][ni] * h0 + eb[mi][ni];
      #pragma unroll
      for (int r = 0; r < 4; r++) {
        h = accz[mi][ni][r] * h + acch[mi][ni][r];
        const int t = wr * 32 + mi * 16 + lg * 4 + r;
        *(u16*)(sub + ((t * 128 + kl2) ^ ((t & 7) << 4))) = f2bf(h);
      }
    }
  }

  #pragma unroll
  for (int i = 0; i < 2; i++)
    #pragma unroll
    for (int j = 0; j < 8; j++) {
      f32x4 zz = {0.f, 0.f, 0.f, 0.f};
      accz[i][j] = zz; acch[i][j] = zz;
    }

  gemm_core(1, WtS, As, Bzs, Bhs, w, wr, wc, l15, lg, lane, accz, acch);

  // ======== layer-1 epilogue: local (A,B) only (no lookback needed) ========
  __syncthreads();
  #pragma unroll
  for (int ni = 0; ni < 8; ni++) {
    const int d = wc * 128 + ni * 16 + l15;
    const float bzv = bz1[d];
    const float bhv = bh1[d];
    #pragma unroll
    for (int mi = 0; mi < 2; mi++) {
      float A = 1.f, B = 0.f;
      #pragma unroll
      for (int r = 0; r < 4; r++) {
        float zl = accz[mi][ni][r] + bzv;
        float zg = 1.f / (1.f + __expf(-zl));
        float ht = acch[mi][ni][r] + bhv;
        float a = 1.f - zg, bb = zg * ht;
        B = B * a + bb;
        A *= a;
      }
      SegT[(wr * 8 + mi * 4 + lg) * 256 + d] = make_float2(A, B);
    }
  }
  __syncthreads();
  if (tid < 256) {
    float PA = 1.f, PB = 0.f;
    #pragma unroll 8
    for (int s = 0; s < 32; s++) {
      float2 v = SegT[s * 256 + tid];
      PB = v.x * PB + v.y;
      PA = v.x * PA;
    }
    Loc1[cb * 256 + tid] = make_float2(PA, PB);
  }
}

// ---------- layer-1 final: serial over chunk locals -> hlast ----------
__global__ void scan2_l1(const float2* __restrict__ Loc1, float* __restrict__ hlast) {
  const int g = blockIdx.x * 256 + threadIdx.x;   // 8192 = 32 b * 256 d
  const int b = g >> 8, d = g & 255;
  float h = 0.f;
  for (int c = 0; c < NCH; c++) {
    float2 v = Loc1[(b * NCH + c) * 256 + d];
    h = v.x * h + v.y;
  }
  hlast[b * 256 + d] = h;
}

__global__ void cls_kernel(const float* __restrict__ hlast, const float* __restrict__ Wo,
                           const float* __restrict__ bo, float* __restrict__ out) {
  const int t = threadIdx.x;       // 256 = 32 b * 8 classes
  const int b = t >> 3, c = t & 7;
  float acc = bo[c];
  for (int d = 0; d < 256; d++) acc += hlast[b * 256 + d] * Wo[d * 8 + c];
  out[t] = acc;
}

extern "C" void kernel_launch(void* const* d_in, const int* in_sizes, int n_in,
                              void* d_out, int out_size, void* d_ws, size_t ws_size,
                              hipStream_t stream) {
  (void)in_sizes; (void)n_in; (void)out_size; (void)ws_size;
  const int*   x   = (const int*)d_in[0];
  const float* emb = (const float*)d_in[1];
  const float* Wz  = (const float*)d_in[2];
  const float* bz  = (const float*)d_in[3];
  const float* Wh  = (const float*)d_in[4];
  const float* bh  = (const float*)d_in[5];
  const float* Wo  = (const float*)d_in[6];
  const float* bo  = (const float*)d_in[7];
  float* out = (float*)d_out;
  char* ws = (char*)d_ws;

  // workspace layout (total ~25.7 MB; ws = 256 MiB)
  u16*    embq  = (u16*)   (ws);                      // 16,384,000 (pad to 16 MiB)
  u16*    WtS   = (u16*)   (ws + 16777216ull);        //    524,288
  u64*    Loc0  = (u64*)   (ws + 17301504ull);        //  4,194,304
  float2* Loc1  = (float2*)(ws + 21495808ull);        //  4,194,304
  float*  hlast = (float*) (ws + 25690112ull);        //     32,768
  int*    syncA = (int*)   (ws + 25722880ull);        //  (1+2048)*4 = 8,196

  embq_kernel<<<8000, 256, 0, stream>>>(emb, embq, syncA);
  wt_kernel<<<1024, 256, 0, stream>>>(Wz, Wh, WtS);

  fused_kernel<<<NBLK, 512, 0, stream>>>(
      x, embq, WtS, bz, bh, bz + 256, bh + 256,
      Loc0, Loc1, syncA + 1, syncA);

  scan2_l1<<<32, 256, 0, stream>>>(Loc1, hlast);
  cls_kernel<<<1, 256, 0, stream>>>(hlast, Wo, bo, out);
}